// Round 1
// baseline (1893.236 us; speedup 1.0000x reference)
//
#include <hip/hip_runtime.h>

// ---------------------------------------------------------------------------
// LLaDA Llama block, MI355X (gfx950).
// Pipeline: convert weights fp32->bf16^T | rmsnorm | QKV GEMMs | RoPE |
//           flash-attn | wo GEMM (+res) | rmsnorm | silu/up GEMMs | out GEMM (+res)
// GEMM = m97 structure: 128x128 tile, BK=32, 4 waves, global_load_lds(16B),
//        ds_read_b128 frags, mfma_f32_16x16x32_bf16, fp32 accum.
// ---------------------------------------------------------------------------

#define D_MODEL 4096
#define FF_DIM  12288
#define SEQ     1024
#define NBATCH  2
#define M_ROWS  2048      // B*T
#define NHEAD   32
#define HDIM    128

typedef short bf16x8 __attribute__((ext_vector_type(8)));
typedef float f32x4  __attribute__((ext_vector_type(4)));

__device__ __forceinline__ ushort f2bf(float f) {          // RNE fp32 -> bf16 bits
  unsigned u = __float_as_uint(f);
  u += 0x7FFFu + ((u >> 16) & 1u);
  return (ushort)(u >> 16);
}
__device__ __forceinline__ float bf2f(ushort u) {
  return __uint_as_float(((unsigned)u) << 16);
}

// async global->LDS, 16B per lane. LDS dest must be wave-uniform base; HW adds lane*16.
#define GLOAD16(gp, lp)                                                        \
  __builtin_amdgcn_global_load_lds(                                            \
      (const __attribute__((address_space(1))) void*)(gp),                     \
      (__attribute__((address_space(3))) void*)(lp), 16, 0, 0)

// ---------------------------------------------------------------------------
// Weight convert+transpose: W (K x N, fp32, row-major) -> Wt (N x K, bf16).
// ---------------------------------------------------------------------------
__global__ __launch_bounds__(256)
void transpose_convert(const float* __restrict__ W, ushort* __restrict__ Wt,
                       int K, int N)
{
  __shared__ float tile[32][33];
  const int x = threadIdx.x, y = threadIdx.y;             // block (32,8)
  const size_t k0 = (size_t)blockIdx.y * 32, n0 = (size_t)blockIdx.x * 32;
#pragma unroll
  for (int i = 0; i < 32; i += 8)
    tile[y + i][x] = W[(k0 + y + i) * N + n0 + x];
  __syncthreads();
#pragma unroll
  for (int i = 0; i < 32; i += 8)
    Wt[(n0 + y + i) * K + k0 + x] = f2bf(tile[x][y + i]);
}

// ---------------------------------------------------------------------------
// RMSNorm: row of 4096 fp32 -> bf16.  1 block (256 thr) per row.
// ---------------------------------------------------------------------------
__global__ __launch_bounds__(256)
void rmsnorm_kernel(const float* __restrict__ x, const float* __restrict__ w,
                    ushort* __restrict__ out)
{
  const int row = blockIdx.x, t = threadIdx.x;
  const float* xr = x + (size_t)row * D_MODEL;
  float4 vv[4];
  float ss = 0.f;
#pragma unroll
  for (int p = 0; p < 4; p++) {
    vv[p] = *(const float4*)&xr[p * 1024 + t * 4];
    ss += vv[p].x * vv[p].x + vv[p].y * vv[p].y + vv[p].z * vv[p].z + vv[p].w * vv[p].w;
  }
#pragma unroll
  for (int mm = 1; mm < 64; mm <<= 1) ss += __shfl_xor(ss, mm);
  __shared__ float wsum[4];
  if ((t & 63) == 0) wsum[t >> 6] = ss;
  __syncthreads();
  ss = wsum[0] + wsum[1] + wsum[2] + wsum[3];
  const float rs = rsqrtf(ss * (1.f / 4096.f) + 1e-5f);
#pragma unroll
  for (int p = 0; p < 4; p++) {
    const float4 wv = *(const float4*)&w[p * 1024 + t * 4];
    ushort4 ov;
    ov.x = f2bf(vv[p].x * rs * wv.x);
    ov.y = f2bf(vv[p].y * rs * wv.y);
    ov.z = f2bf(vv[p].z * rs * wv.z);
    ov.w = f2bf(vv[p].w * rs * wv.w);
    *(ushort4*)&out[(size_t)row * D_MODEL + p * 1024 + t * 4] = ov;
  }
}

// ---------------------------------------------------------------------------
// RoPE in-place on q and k (bf16). One thread per (t, h, d<64) pair.
// ---------------------------------------------------------------------------
__global__ __launch_bounds__(256)
void rope_kernel(ushort* __restrict__ q, ushort* __restrict__ k,
                 const float* __restrict__ sinp, const float* __restrict__ cosp)
{
  const size_t idx = (size_t)blockIdx.x * 256 + threadIdx.x;   // < 2048*32*64
  const int d = (int)(idx & 63);
  const int h = (int)((idx >> 6) & 31);
  const int t = (int)(idx >> 11);
  const float s = sinp[t * 64 + d], c = cosp[t * 64 + d];
  const size_t base = (size_t)t * D_MODEL + h * HDIM + d;
  const float q1 = bf2f(q[base]), q2 = bf2f(q[base + 64]);
  q[base]      = f2bf(q1 * c - q2 * s);
  q[base + 64] = f2bf(q2 * c + q1 * s);
  const float k1 = bf2f(k[base]), k2 = bf2f(k[base + 64]);
  k[base]      = f2bf(k1 * c - k2 * s);
  k[base + 64] = f2bf(k2 * c + k1 * s);
}

// ---------------------------------------------------------------------------
// Flash attention fwd. 1 wave per (b, h, 16-row Q tile). No mask.
// QK^T: A=Q frag, B=K frag (both k-contiguous loads from global).
// C/D layout (m89): col = lane&15, row = (lane>>4)*4 + reg.
// P transposed via 1KB LDS; V read scalar from global (L2-resident).
// ---------------------------------------------------------------------------
__global__ __launch_bounds__(64)
void attn_fwd(const ushort* __restrict__ q, const ushort* __restrict__ k,
              const ushort* __restrict__ v, ushort* __restrict__ o)
{
  const int l = threadIdx.x, c16 = l & 15, g = l >> 4;
  const int qt = blockIdx.x, h = blockIdx.y, b = blockIdx.z;
  __shared__ __align__(16) ushort P_lds[16 * 32];

  const size_t head_off = (size_t)h * HDIM;
  const size_t rowQ = (size_t)(b * SEQ + qt * 16 + c16);
  bf16x8 qf[4];
#pragma unroll
  for (int kc = 0; kc < 4; kc++)
    qf[kc] = *(const bf16x8*)(q + rowQ * D_MODEL + head_off + kc * 32 + g * 8);

  f32x4 oacc[8];
#pragma unroll
  for (int i = 0; i < 8; i++) oacc[i] = (f32x4){0.f, 0.f, 0.f, 0.f};
  float mrow[4] = {-1e30f, -1e30f, -1e30f, -1e30f};
  float lrow[4] = {0.f, 0.f, 0.f, 0.f};
  const float scale = 0.08838834764831845f;   // 1/sqrt(128)
  const float L2E = 1.4426950408889634f;

  for (int s0 = 0; s0 < SEQ; s0 += 32) {
    f32x4 st[2];
#pragma unroll
    for (int t = 0; t < 2; t++) {
      f32x4 a = (f32x4){0.f, 0.f, 0.f, 0.f};
      const ushort* kb = k + (size_t)(b * SEQ + s0 + t * 16 + c16) * D_MODEL + head_off + g * 8;
#pragma unroll
      for (int kc = 0; kc < 4; kc++) {
        bf16x8 kf = *(const bf16x8*)(kb + kc * 32);
        a = __builtin_amdgcn_mfma_f32_16x16x32_bf16(qf[kc], kf, a, 0, 0, 0);
      }
      st[t] = a;
    }
    // online softmax; lane holds S[q = g*4+r][s = s0 + t*16 + c16]
#pragma unroll
    for (int r = 0; r < 4; r++) {
      const float s0v = st[0][r] * scale, s1v = st[1][r] * scale;
      float cm = fmaxf(s0v, s1v);
#pragma unroll
      for (int mm = 1; mm < 16; mm <<= 1) cm = fmaxf(cm, __shfl_xor(cm, mm));
      const float mn = fmaxf(mrow[r], cm);
      const float alpha = exp2f((mrow[r] - mn) * L2E);
      const float p0 = exp2f((s0v - mn) * L2E);
      const float p1 = exp2f((s1v - mn) * L2E);
      float rsum = p0 + p1;
#pragma unroll
      for (int mm = 1; mm < 16; mm <<= 1) rsum += __shfl_xor(rsum, mm);
      lrow[r] = lrow[r] * alpha + rsum;
      mrow[r] = mn;
#pragma unroll
      for (int dbi = 0; dbi < 8; dbi++) oacc[dbi] *= alpha;
      P_lds[(g * 4 + r) * 32 + c16]      = f2bf(p0);
      P_lds[(g * 4 + r) * 32 + 16 + c16] = f2bf(p1);
    }
    __syncthreads();
    // PV: A = P[q=c16][s=g*8+j] (b128 from LDS), B = V[s][d] scalar from global
    const bf16x8 pf = *(const bf16x8*)&P_lds[c16 * 32 + g * 8];
#pragma unroll
    for (int dbi = 0; dbi < 8; dbi++) {
      bf16x8 vf;
      const ushort* vb = v + (size_t)(b * SEQ + s0 + g * 8) * D_MODEL + head_off + dbi * 16 + c16;
#pragma unroll
      for (int j = 0; j < 8; j++) vf[j] = (short)vb[(size_t)j * D_MODEL];
      oacc[dbi] = __builtin_amdgcn_mfma_f32_16x16x32_bf16(pf, vf, oacc[dbi], 0, 0, 0);
    }
    __syncthreads();
  }
  const size_t rowO = (size_t)(b * SEQ + qt * 16 + g * 4);
#pragma unroll
  for (int dbi = 0; dbi < 8; dbi++)
#pragma unroll
    for (int r = 0; r < 4; r++)
      o[(rowO + r) * D_MODEL + head_off + dbi * 16 + c16] = f2bf(oacc[dbi][r] / lrow[r]);
}

// ---------------------------------------------------------------------------
// GEMM: C[M,N] = A[M,K] @ Bt[N,K]^T, bf16 inputs, fp32 accum.
// EPI 0: C bf16 | 1: C fp32 = res + acc | 2: C bf16 = silu(acc) | 3: aux *= acc (bf16, in place)
// ---------------------------------------------------------------------------
template <int EPI>
__global__ __launch_bounds__(256)
void gemm_bt(const ushort* __restrict__ A, const ushort* __restrict__ Bt,
             const float* __restrict__ res, ushort* __restrict__ aux,
             void* __restrict__ Cout, int M, int N, int K)
{
  __shared__ __align__(16) ushort As[128 * 32];
  __shared__ __align__(16) ushort Bs[128 * 32];
  const int tid = threadIdx.x;
  const int l = tid & 63, w = tid >> 6;
  const int wr = w >> 1, wc = w & 1;          // 2x2 wave grid, 64x64 per wave
  const int c16 = l & 15, g = l >> 4;
  const int m0 = blockIdx.y * 128, n0 = blockIdx.x * 128;

  f32x4 acc[4][4];
#pragma unroll
  for (int i = 0; i < 4; i++)
#pragma unroll
    for (int j = 0; j < 4; j++) acc[i][j] = (f32x4){0.f, 0.f, 0.f, 0.f};

  // staging addressing: thread t -> row (t>>2), k-elem-offset (t&3)*8 (16B)
  const int rowS = tid >> 2;
  const int kofs = (tid & 3) * 8;
  const ushort* gA = A + (size_t)(m0 + rowS) * K + kofs;
  const ushort* gB = Bt + (size_t)(n0 + rowS) * K + kofs;
  ushort* lA0 = &As[w * 512];          ushort* lA1 = &As[2048 + w * 512];
  ushort* lB0 = &Bs[w * 512];          ushort* lB1 = &Bs[2048 + w * 512];

  for (int k0 = 0; k0 < K; k0 += 32) {
    GLOAD16(gA + k0, lA0);
    GLOAD16(gA + k0 + (size_t)64 * K, lA1);
    GLOAD16(gB + k0, lB0);
    GLOAD16(gB + k0 + (size_t)64 * K, lB1);
    __syncthreads();
    bf16x8 af[4], bfr[4];
#pragma unroll
    for (int i = 0; i < 4; i++) {
      af[i]  = *(const bf16x8*)&As[(wr * 64 + i * 16 + c16) * 32 + g * 8];
      bfr[i] = *(const bf16x8*)&Bs[(wc * 64 + i * 16 + c16) * 32 + g * 8];
    }
#pragma unroll
    for (int i = 0; i < 4; i++)
#pragma unroll
      for (int j = 0; j < 4; j++)
        acc[i][j] = __builtin_amdgcn_mfma_f32_16x16x32_bf16(af[i], bfr[j], acc[i][j], 0, 0, 0);
    __syncthreads();
  }

#pragma unroll
  for (int i = 0; i < 4; i++)
#pragma unroll
    for (int j = 0; j < 4; j++)
#pragma unroll
      for (int r = 0; r < 4; r++) {
        const int row = m0 + wr * 64 + i * 16 + g * 4 + r;
        const int col = n0 + wc * 64 + j * 16 + c16;
        const size_t idx = (size_t)row * N + col;
        const float vacc = acc[i][j][r];
        if constexpr (EPI == 0) {
          ((ushort*)Cout)[idx] = f2bf(vacc);
        } else if constexpr (EPI == 1) {
          ((float*)Cout)[idx] = res[idx] + vacc;
        } else if constexpr (EPI == 2) {
          ((ushort*)Cout)[idx] = f2bf(vacc / (1.f + __expf(-vacc)));
        } else {
          const float hv = bf2f(aux[idx]) * vacc;
          aux[idx] = f2bf(hv);
        }
      }
}

// ---------------------------------------------------------------------------
extern "C" void kernel_launch(void* const* d_in, const int* in_sizes, int n_in,
                              void* d_out, int out_size, void* d_ws, size_t ws_size,
                              hipStream_t stream)
{
  const float* x    = (const float*)d_in[0];
  const float* sinp = (const float*)d_in[1];
  const float* cosp = (const float*)d_in[2];
  const float* anw  = (const float*)d_in[3];
  const float* fnw  = (const float*)d_in[4];
  const float* wq   = (const float*)d_in[5];
  const float* wk   = (const float*)d_in[6];
  const float* wv   = (const float*)d_in[7];
  const float* wo   = (const float*)d_in[8];
  const float* wff  = (const float*)d_in[9];
  const float* wup  = (const float*)d_in[10];
  const float* wout = (const float*)d_in[11];
  float* out = (float*)d_out;

  const size_t szDD   = (size_t)D_MODEL * D_MODEL * 2;   // 33.55 MB
  const size_t szDF   = (size_t)D_MODEL * FF_DIM * 2;    // 100.66 MB
  const size_t szAct2 = (size_t)M_ROWS * D_MODEL * 2;    // 16.78 MB
  const size_t szAct4 = (size_t)M_ROWS * D_MODEL * 4;    // 33.55 MB
  const size_t szFF2  = (size_t)M_ROWS * FF_DIM * 2;     // 50.33 MB

  char* ws = (char*)d_ws;
  size_t off = 0;
  auto alloc = [&](size_t bytes) -> char* {
    char* p = ws + off;
    off += (bytes + 255) & ~(size_t)255;
    return p;
  };
  ushort* wqt   = (ushort*)alloc(szDD);
  ushort* wkt   = (ushort*)alloc(szDD);
  ushort* wvt   = (ushort*)alloc(szDD);
  ushort* wot   = (ushort*)alloc(szDD);
  ushort* wfft  = (ushort*)alloc(szDF);
  ushort* wupt  = (ushort*)alloc(szDF);
  ushort* woutt = (ushort*)alloc(szDF);
  ushort* xn    = (ushort*)alloc(szAct2);
  ushort* qb    = (ushort*)alloc(szAct2);
  ushort* kb    = (ushort*)alloc(szAct2);
  ushort* vb    = (ushort*)alloc(szAct2);
  ushort* attnb = (ushort*)alloc(szAct2);
  float*  x2    = (float*)alloc(szAct4);
  ushort* ffb   = (ushort*)alloc(szFF2);
  if (off > ws_size) return;   // insufficient workspace -> visible absmax failure, no corruption

  const dim3 tb(32, 8);
  // weight conversions: W(K,N) fp32 -> Wt(N,K) bf16
  transpose_convert<<<dim3(D_MODEL / 32, D_MODEL / 32), tb, 0, stream>>>(wq, wqt, D_MODEL, D_MODEL);
  transpose_convert<<<dim3(D_MODEL / 32, D_MODEL / 32), tb, 0, stream>>>(wk, wkt, D_MODEL, D_MODEL);
  transpose_convert<<<dim3(D_MODEL / 32, D_MODEL / 32), tb, 0, stream>>>(wv, wvt, D_MODEL, D_MODEL);
  transpose_convert<<<dim3(D_MODEL / 32, D_MODEL / 32), tb, 0, stream>>>(wo, wot, D_MODEL, D_MODEL);
  transpose_convert<<<dim3(FF_DIM / 32, D_MODEL / 32), tb, 0, stream>>>(wff, wfft, D_MODEL, FF_DIM);
  transpose_convert<<<dim3(FF_DIM / 32, D_MODEL / 32), tb, 0, stream>>>(wup, wupt, D_MODEL, FF_DIM);
  transpose_convert<<<dim3(D_MODEL / 32, FF_DIM / 32), tb, 0, stream>>>(wout, woutt, FF_DIM, D_MODEL);

  // attn branch
  rmsnorm_kernel<<<M_ROWS, 256, 0, stream>>>(x, anw, xn);
  gemm_bt<0><<<dim3(D_MODEL / 128, M_ROWS / 128), 256, 0, stream>>>(xn, wqt, nullptr, nullptr, qb, M_ROWS, D_MODEL, D_MODEL);
  gemm_bt<0><<<dim3(D_MODEL / 128, M_ROWS / 128), 256, 0, stream>>>(xn, wkt, nullptr, nullptr, kb, M_ROWS, D_MODEL, D_MODEL);
  gemm_bt<0><<<dim3(D_MODEL / 128, M_ROWS / 128), 256, 0, stream>>>(xn, wvt, nullptr, nullptr, vb, M_ROWS, D_MODEL, D_MODEL);
  rope_kernel<<<(M_ROWS * NHEAD * 64) / 256, 256, 0, stream>>>(qb, kb, sinp, cosp);
  attn_fwd<<<dim3(SEQ / 16, NHEAD, NBATCH), 64, 0, stream>>>(qb, kb, vb, attnb);
  gemm_bt<1><<<dim3(D_MODEL / 128, M_ROWS / 128), 256, 0, stream>>>(attnb, wot, x, nullptr, x2, M_ROWS, D_MODEL, D_MODEL);

  // ffn branch
  rmsnorm_kernel<<<M_ROWS, 256, 0, stream>>>(x2, fnw, xn);
  gemm_bt<2><<<dim3(FF_DIM / 128, M_ROWS / 128), 256, 0, stream>>>(xn, wfft, nullptr, nullptr, ffb, M_ROWS, FF_DIM, D_MODEL);
  gemm_bt<3><<<dim3(FF_DIM / 128, M_ROWS / 128), 256, 0, stream>>>(xn, wupt, nullptr, ffb, nullptr, M_ROWS, FF_DIM, D_MODEL);
  gemm_bt<1><<<dim3(D_MODEL / 128, M_ROWS / 128), 256, 0, stream>>>(ffb, woutt, x2, nullptr, out, M_ROWS, D_MODEL, FF_DIM);
}

// Round 2
// 1543.687 us; speedup vs baseline: 1.2264x; 1.2264x over previous
//
#include <hip/hip_runtime.h>

// ---------------------------------------------------------------------------
// LLaDA Llama block, MI355X (gfx950). Round 2.
// GEMMs ported to the 256x256 8-phase template (T1 XCD swizzle, T2 LDS XOR
// swizzle, T3/T4 counted-vmcnt 8-phase, T5 setprio). QKV fused (N=12288),
// ff|up fused (N=24576) + elementwise SwiGLU.
// ---------------------------------------------------------------------------

#define D_MODEL 4096
#define FF_DIM  12288
#define SEQ     1024
#define NBATCH  2
#define M_ROWS  2048
#define NHEAD   32
#define HDIM    128
#define QKV_N   12288
#define FF2_N   24576

typedef short bf16x8 __attribute__((ext_vector_type(8)));
typedef float f32x4  __attribute__((ext_vector_type(4)));

__device__ __forceinline__ ushort f2bf(float f) {
  unsigned u = __float_as_uint(f);
  u += 0x7FFFu + ((u >> 16) & 1u);
  return (ushort)(u >> 16);
}
__device__ __forceinline__ float bf2f(ushort u) {
  return __uint_as_float(((unsigned)u) << 16);
}

__device__ __forceinline__ void gload_lds16(const ushort* gsrc, ushort* ldst) {
  __builtin_amdgcn_global_load_lds((const __attribute__((address_space(1))) void*)gsrc,
                                   (__attribute__((address_space(3))) void*)ldst, 16, 0, 0);
}

#define SBAR()  asm volatile("s_barrier" ::: "memory")
#define LGKM0() asm volatile("s_waitcnt lgkmcnt(0)" ::: "memory")
#define VMCNT6() asm volatile("s_waitcnt vmcnt(6)" ::: "memory")

// ---------------------------------------------------------------------------
// Weight convert+transpose: W (K x N, fp32, row-major) -> Wt (N x K, bf16).
// ---------------------------------------------------------------------------
__global__ __launch_bounds__(256)
void transpose_convert(const float* __restrict__ W, ushort* __restrict__ Wt,
                       int K, int N)
{
  __shared__ float tile[32][33];
  const int x = threadIdx.x, y = threadIdx.y;             // block (32,8)
  const size_t k0 = (size_t)blockIdx.y * 32, n0 = (size_t)blockIdx.x * 32;
#pragma unroll
  for (int i = 0; i < 32; i += 8)
    tile[y + i][x] = W[(k0 + y + i) * N + n0 + x];
  __syncthreads();
#pragma unroll
  for (int i = 0; i < 32; i += 8)
    Wt[(n0 + y + i) * K + k0 + x] = f2bf(tile[x][y + i]);
}

// ---------------------------------------------------------------------------
// RMSNorm: row of 4096 fp32 -> bf16.  1 block (256 thr) per row.
// ---------------------------------------------------------------------------
__global__ __launch_bounds__(256)
void rmsnorm_kernel(const float* __restrict__ x, const float* __restrict__ w,
                    ushort* __restrict__ out)
{
  const int row = blockIdx.x, t = threadIdx.x;
  const float* xr = x + (size_t)row * D_MODEL;
  float4 vv[4];
  float ss = 0.f;
#pragma unroll
  for (int p = 0; p < 4; p++) {
    vv[p] = *(const float4*)&xr[p * 1024 + t * 4];
    ss += vv[p].x * vv[p].x + vv[p].y * vv[p].y + vv[p].z * vv[p].z + vv[p].w * vv[p].w;
  }
#pragma unroll
  for (int mm = 1; mm < 64; mm <<= 1) ss += __shfl_xor(ss, mm);
  __shared__ float wsum[4];
  if ((t & 63) == 0) wsum[t >> 6] = ss;
  __syncthreads();
  ss = wsum[0] + wsum[1] + wsum[2] + wsum[3];
  const float rs = rsqrtf(ss * (1.f / 4096.f) + 1e-5f);
#pragma unroll
  for (int p = 0; p < 4; p++) {
    const float4 wv = *(const float4*)&w[p * 1024 + t * 4];
    ushort4 ov;
    ov.x = f2bf(vv[p].x * rs * wv.x);
    ov.y = f2bf(vv[p].y * rs * wv.y);
    ov.z = f2bf(vv[p].z * rs * wv.z);
    ov.w = f2bf(vv[p].w * rs * wv.w);
    *(ushort4*)&out[(size_t)row * D_MODEL + p * 1024 + t * 4] = ov;
  }
}

// ---------------------------------------------------------------------------
// RoPE in-place on q and k columns of the fused qkv buffer (ld = 12288).
// ---------------------------------------------------------------------------
__global__ __launch_bounds__(256)
void rope_kernel(ushort* __restrict__ q, ushort* __restrict__ k,
                 const float* __restrict__ sinp, const float* __restrict__ cosp,
                 int ld)
{
  const size_t idx = (size_t)blockIdx.x * 256 + threadIdx.x;   // < 2048*32*64
  const int d = (int)(idx & 63);
  const int h = (int)((idx >> 6) & 31);
  const int t = (int)(idx >> 11);
  const float s = sinp[t * 64 + d], c = cosp[t * 64 + d];
  const size_t base = (size_t)t * ld + h * HDIM + d;
  const float q1 = bf2f(q[base]), q2 = bf2f(q[base + 64]);
  q[base]      = f2bf(q1 * c - q2 * s);
  q[base + 64] = f2bf(q2 * c + q1 * s);
  const float k1 = bf2f(k[base]), k2 = bf2f(k[base + 64]);
  k[base]      = f2bf(k1 * c - k2 * s);
  k[base + 64] = f2bf(k2 * c + k1 * s);
}

// ---------------------------------------------------------------------------
// Flash attention fwd. 1 wave per (b, h, 16-row Q tile). No mask.
// q/k/v may live in a fused buffer with leading dim ldq; output ldo = 4096.
// ---------------------------------------------------------------------------
__global__ __launch_bounds__(64)
void attn_fwd(const ushort* __restrict__ q, const ushort* __restrict__ k,
              const ushort* __restrict__ v, ushort* __restrict__ o,
              int ldq, int ldo)
{
  const int l = threadIdx.x, c16 = l & 15, g = l >> 4;
  const int qt = blockIdx.x, h = blockIdx.y, b = blockIdx.z;
  __shared__ __align__(16) ushort P_lds[16 * 32];

  const size_t head_off = (size_t)h * HDIM;
  const size_t rowQ = (size_t)(b * SEQ + qt * 16 + c16);
  bf16x8 qf[4];
#pragma unroll
  for (int kc = 0; kc < 4; kc++)
    qf[kc] = *(const bf16x8*)(q + rowQ * ldq + head_off + kc * 32 + g * 8);

  f32x4 oacc[8];
#pragma unroll
  for (int i = 0; i < 8; i++) oacc[i] = (f32x4){0.f, 0.f, 0.f, 0.f};
  float mrow[4] = {-1e30f, -1e30f, -1e30f, -1e30f};
  float lrow[4] = {0.f, 0.f, 0.f, 0.f};
  const float scale = 0.08838834764831845f;   // 1/sqrt(128)
  const float L2E = 1.4426950408889634f;

  for (int s0 = 0; s0 < SEQ; s0 += 32) {
    f32x4 st[2];
#pragma unroll
    for (int t = 0; t < 2; t++) {
      f32x4 a = (f32x4){0.f, 0.f, 0.f, 0.f};
      const ushort* kb = k + (size_t)(b * SEQ + s0 + t * 16 + c16) * ldq + head_off + g * 8;
#pragma unroll
      for (int kc = 0; kc < 4; kc++) {
        bf16x8 kf = *(const bf16x8*)(kb + kc * 32);
        a = __builtin_amdgcn_mfma_f32_16x16x32_bf16(qf[kc], kf, a, 0, 0, 0);
      }
      st[t] = a;
    }
#pragma unroll
    for (int r = 0; r < 4; r++) {
      const float s0v = st[0][r] * scale, s1v = st[1][r] * scale;
      float cm = fmaxf(s0v, s1v);
#pragma unroll
      for (int mm = 1; mm < 16; mm <<= 1) cm = fmaxf(cm, __shfl_xor(cm, mm));
      const float mn = fmaxf(mrow[r], cm);
      const float alpha = exp2f((mrow[r] - mn) * L2E);
      const float p0 = exp2f((s0v - mn) * L2E);
      const float p1 = exp2f((s1v - mn) * L2E);
      float rsum = p0 + p1;
#pragma unroll
      for (int mm = 1; mm < 16; mm <<= 1) rsum += __shfl_xor(rsum, mm);
      lrow[r] = lrow[r] * alpha + rsum;
      mrow[r] = mn;
#pragma unroll
      for (int dbi = 0; dbi < 8; dbi++) oacc[dbi] *= alpha;
      P_lds[(g * 4 + r) * 32 + c16]      = f2bf(p0);
      P_lds[(g * 4 + r) * 32 + 16 + c16] = f2bf(p1);
    }
    __syncthreads();
    const bf16x8 pf = *(const bf16x8*)&P_lds[c16 * 32 + g * 8];
#pragma unroll
    for (int dbi = 0; dbi < 8; dbi++) {
      bf16x8 vf;
      const ushort* vb = v + (size_t)(b * SEQ + s0 + g * 8) * ldq + head_off + dbi * 16 + c16;
#pragma unroll
      for (int j = 0; j < 8; j++) vf[j] = (short)vb[(size_t)j * ldq];
      oacc[dbi] = __builtin_amdgcn_mfma_f32_16x16x32_bf16(pf, vf, oacc[dbi], 0, 0, 0);
    }
    __syncthreads();
  }
  const size_t rowO = (size_t)(b * SEQ + qt * 16 + g * 4);
#pragma unroll
  for (int dbi = 0; dbi < 8; dbi++)
#pragma unroll
    for (int r = 0; r < 4; r++)
      o[(rowO + r) * ldo + head_off + dbi * 16 + c16] = f2bf(oacc[dbi][r] / lrow[r]);
}

// ---------------------------------------------------------------------------
// SwiGLU elementwise: hraw [M][24576] bf16 (cols 0..12287 = h, 12288.. = up)
// -> g [M][12288] bf16 = silu(h) * up
// ---------------------------------------------------------------------------
__global__ __launch_bounds__(256)
void swiglu_kernel(const ushort* __restrict__ hraw, ushort* __restrict__ g)
{
  const int m = blockIdx.y;
  const int c = (blockIdx.x * 256 + threadIdx.x) * 8;
  const ushort* hp = hraw + (size_t)m * FF2_N + c;
  bf16x8 hv = *(const bf16x8*)hp;
  bf16x8 uv = *(const bf16x8*)(hp + FF_DIM);
  bf16x8 ov;
#pragma unroll
  for (int e = 0; e < 8; e++) {
    const float h = bf2f((ushort)hv[e]);
    const float u = bf2f((ushort)uv[e]);
    ov[e] = (short)f2bf((h / (1.f + __expf(-h))) * u);
  }
  *(bf16x8*)(g + (size_t)m * FF_DIM + c) = ov;
}

// ---------------------------------------------------------------------------
// 256x256 8-phase GEMM (T1+T2+T3+T4+T5). C[M,N] = A[M,K] @ Bt[N,K]^T.
// 512 thr = 8 waves (2Mx4N); per-wave C = 128x64 as quadrants of 64x32.
// LDS 128KB: A bufs [0,64KB) = 2 x 256x64 bf16; B bufs [64KB,128KB).
// rows = qm*128 + wr*64 + i*16 + c16  (qm selects A-half)
// cols = qn*128 + wc*32 + j*16 + c16  (qn selects B-half)
// Staging rhythm (per tile t, parity p): P1: (t+1).A-h1 -> p^1;
// P2: (t+2).A-h0 -> p; P3: (t+2).B-h0 -> p; P4: (t+2).B-h1 -> p; vmcnt(6).
// Each target region's last reader finished >=1 barrier before the issue.
// XOR swizzle (T2): LDS linear dest, source col ^= ((row&7)<<4) bytes,
// ds_read col ^= same -> 2-way max conflict on ds_read_b128.
// EPI 0: C bf16 | 1: C fp32 = res + acc
// ---------------------------------------------------------------------------
template <int EPI>
__global__ __launch_bounds__(512, 2)
void gemm8p(const ushort* __restrict__ A, const ushort* __restrict__ Bt,
            const float* __restrict__ res, void* __restrict__ Cout,
            int M, int N, int K)
{
  __shared__ __align__(16) ushort lds[65536];   // 128 KB
  const int tid = threadIdx.x;
  const int w = tid >> 6, l = tid & 63;
  const int c16 = l & 15, g = l >> 4;
  const int wr = w >> 2, wc = w & 3;

  // T1: bijective XCD swizzle (m204)
  const int nx = N >> 8;
  const int nwg = gridDim.x;
  const int q8 = nwg >> 3, r8 = nwg & 7;
  const int xcd = blockIdx.x & 7, loc = blockIdx.x >> 3;
  const int wg = (xcd < r8 ? xcd * (q8 + 1) : r8 * (q8 + 1) + (xcd - r8) * q8) + loc;
  const size_t m0 = (size_t)(wg / nx) * 256;
  const size_t n0 = (size_t)(wg % nx) * 256;
  const int nk = K >> 6;

  // staging per-thread constants (16B per lane, 2 gloads per 128x64 half-tile)
  const int srow  = (w << 3) + (l >> 3);              // row within 64-row chunk
  const int scolE = ((l & 7) ^ (l >> 3)) << 3;        // swizzled source col (elems)
  const ushort* gA = A  + (m0 + srow) * (size_t)K + scolE;
  const ushort* gB = Bt + (n0 + srow) * (size_t)K + scolE;

#define STG_A(p, h, q, tk)                                                        \
  gload_lds16(gA + (size_t)((h) * 128 + (q) * 64) * K + (size_t)(tk) * 64,        \
              lds + (p) * 16384 + (h) * 8192 + (q) * 4096 + (w << 9))
#define STG_B(p, h, q, tk)                                                        \
  gload_lds16(gB + (size_t)((h) * 128 + (q) * 64) * K + (size_t)(tk) * 64,        \
              lds + 32768 + (p) * 16384 + (h) * 8192 + (q) * 4096 + (w << 9))
#define STG_A2(p, h, tk) do { STG_A(p, h, 0, tk); STG_A(p, h, 1, tk); } while (0)
#define STG_B2(p, h, tk) do { STG_B(p, h, 0, tk); STG_B(p, h, 1, tk); } while (0)

  // fragment read constants
  const int xorE = (c16 & 7) << 3;
  const int k0E = (g * 8) ^ xorE;          // kk = 0
  const int k1E = (32 + g * 8) ^ xorE;     // kk = 1
  const int aRow = wr * 64 + c16;
  const int bRow = wc * 32 + c16;

  auto LDA = [&](int p, int qm, int i, int ke) -> bf16x8 {
    return *(const bf16x8*)(lds + p * 16384 + (qm * 128 + aRow + i * 16) * 64 + ke);
  };
  auto LDB = [&](int p, int qn, int j, int ke) -> bf16x8 {
    return *(const bf16x8*)(lds + 32768 + p * 16384 + (qn * 128 + bRow + j * 16) * 64 + ke);
  };

  f32x4 acc[8][4];
#pragma unroll
  for (int i = 0; i < 8; i++)
#pragma unroll
    for (int j = 0; j < 4; j++) acc[i][j] = (f32x4){0.f, 0.f, 0.f, 0.f};
  bf16x8 a[4][2], b0[2][2], b1[2][2];

  // prologue: tile0 all 4 half-tiles, tile1 {A-h0, B-h0, B-h1}
  STG_A2(0, 0, 0); STG_A2(0, 1, 0); STG_B2(0, 0, 0); STG_B2(0, 1, 0);
  STG_A2(1, 0, 1); STG_B2(1, 0, 1); STG_B2(1, 1, 1);
  VMCNT6(); SBAR();

  for (int t = 0; t < nk; ++t) {
    const int p = t & 1;
    const int tn1 = (t + 1 < nk) ? t + 1 : t + 1 - nk;   // wrapped (garbage tiles
    const int tn2 = (t + 2 < nk) ? t + 2 : t + 2 - nk;   // never read)

    // ---- phase 1: quadrant (0,0): read A[qm0] + B[qn0]
#pragma unroll
    for (int i = 0; i < 4; ++i) { a[i][0] = LDA(p, 0, i, k0E); a[i][1] = LDA(p, 0, i, k1E); }
#pragma unroll
    for (int j = 0; j < 2; ++j) { b0[j][0] = LDB(p, 0, j, k0E); b0[j][1] = LDB(p, 0, j, k1E); }
    STG_A2(p ^ 1, 1, tn1);
    SBAR(); LGKM0();
    __builtin_amdgcn_s_setprio(1);
#pragma unroll
    for (int i = 0; i < 4; ++i)
#pragma unroll
      for (int j = 0; j < 2; ++j)
#pragma unroll
        for (int kk = 0; kk < 2; ++kk)
          acc[i][j] = __builtin_amdgcn_mfma_f32_16x16x32_bf16(a[i][kk], b0[j][kk], acc[i][j], 0, 0, 0);
    __builtin_amdgcn_s_setprio(0);
    SBAR();

    // ---- phase 2: quadrant (0,1): read B[qn1]
#pragma unroll
    for (int j = 0; j < 2; ++j) { b1[j][0] = LDB(p, 1, j, k0E); b1[j][1] = LDB(p, 1, j, k1E); }
    STG_A2(p, 0, tn2);
    SBAR(); LGKM0();
    __builtin_amdgcn_s_setprio(1);
#pragma unroll
    for (int i = 0; i < 4; ++i)
#pragma unroll
      for (int j = 0; j < 2; ++j)
#pragma unroll
        for (int kk = 0; kk < 2; ++kk)
          acc[i][2 + j] = __builtin_amdgcn_mfma_f32_16x16x32_bf16(a[i][kk], b1[j][kk], acc[i][2 + j], 0, 0, 0);
    __builtin_amdgcn_s_setprio(0);
    SBAR();

    // ---- phase 3: quadrant (1,0): read A[qm1]
#pragma unroll
    for (int i = 0; i < 4; ++i) { a[i][0] = LDA(p, 1, i, k0E); a[i][1] = LDA(p, 1, i, k1E); }
    STG_B2(p, 0, tn2);
    SBAR(); LGKM0();
    __builtin_amdgcn_s_setprio(1);
#pragma unroll
    for (int i = 0; i < 4; ++i)
#pragma unroll
      for (int j = 0; j < 2; ++j)
#pragma unroll
        for (int kk = 0; kk < 2; ++kk)
          acc[4 + i][j] = __builtin_amdgcn_mfma_f32_16x16x32_bf16(a[i][kk], b0[j][kk], acc[4 + i][j], 0, 0, 0);
    __builtin_amdgcn_s_setprio(0);
    SBAR();

    // ---- phase 4: quadrant (1,1): no ds_read
    STG_B2(p, 1, tn2);
    SBAR(); LGKM0();
    __builtin_amdgcn_s_setprio(1);
#pragma unroll
    for (int i = 0; i < 4; ++i)
#pragma unroll
      for (int j = 0; j < 2; ++j)
#pragma unroll
        for (int kk = 0; kk < 2; ++kk)
          acc[4 + i][2 + j] = __builtin_amdgcn_mfma_f32_16x16x32_bf16(a[i][kk], b1[j][kk], acc[4 + i][2 + j], 0, 0, 0);
    __builtin_amdgcn_s_setprio(0);
    VMCNT6(); SBAR();
  }

  // epilogue
#pragma unroll
  for (int qm = 0; qm < 2; qm++)
#pragma unroll
    for (int i = 0; i < 4; i++)
#pragma unroll
      for (int qn = 0; qn < 2; qn++)
#pragma unroll
        for (int j = 0; j < 2; j++)
#pragma unroll
          for (int r = 0; r < 4; r++) {
            const size_t row = m0 + qm * 128 + wr * 64 + i * 16 + g * 4 + r;
            const size_t col = n0 + qn * 128 + wc * 32 + j * 16 + c16;
            const size_t idx = row * N + col;
            const float v = acc[qm * 4 + i][qn * 2 + j][r];
            if constexpr (EPI == 0) {
              ((ushort*)Cout)[idx] = f2bf(v);
            } else {
              ((float*)Cout)[idx] = res[idx] + v;
            }
          }
#undef STG_A
#undef STG_B
#undef STG_A2
#undef STG_B2
}

// ---------------------------------------------------------------------------
extern "C" void kernel_launch(void* const* d_in, const int* in_sizes, int n_in,
                              void* d_out, int out_size, void* d_ws, size_t ws_size,
                              hipStream_t stream)
{
  const float* x    = (const float*)d_in[0];
  const float* sinp = (const float*)d_in[1];
  const float* cosp = (const float*)d_in[2];
  const float* anw  = (const float*)d_in[3];
  const float* fnw  = (const float*)d_in[4];
  const float* wq   = (const float*)d_in[5];
  const float* wk   = (const float*)d_in[6];
  const float* wv   = (const float*)d_in[7];
  const float* wo   = (const float*)d_in[8];
  const float* wff  = (const float*)d_in[9];
  const float* wup  = (const float*)d_in[10];
  const float* wout = (const float*)d_in[11];
  float* out = (float*)d_out;

  const size_t szDD   = (size_t)D_MODEL * D_MODEL * 2;     // 33.55 MB
  const size_t szDF   = (size_t)D_MODEL * FF_DIM * 2;      // 100.66 MB
  const size_t szAct2 = (size_t)M_ROWS * D_MODEL * 2;      // 16.78 MB
  const size_t szAct4 = (size_t)M_ROWS * D_MODEL * 4;      // 33.55 MB
  const size_t szQKV  = (size_t)M_ROWS * QKV_N * 2;        // 50.33 MB
  const size_t szFF2  = (size_t)M_ROWS * FF2_N * 2;        // 100.66 MB

  char* ws = (char*)d_ws;
  size_t off = 0;
  auto alloc = [&](size_t bytes) -> char* {
    char* p = ws + off;
    off += (bytes + 255) & ~(size_t)255;
    return p;
  };
  ushort* R1    = (ushort*)alloc(szDF);    // wq|wk|wv^T, later wout^T
  ushort* R2    = (ushort*)alloc(2 * szDF);// wff^T | wup^T  (24576 x 4096)
  ushort* wot   = (ushort*)alloc(szDD);
  ushort* xn    = (ushort*)alloc(szAct2);
  ushort* qkv   = (ushort*)alloc(szQKV);   // later reused as g (swiglu out)
  ushort* attnb = (ushort*)alloc(szAct2);
  float*  x2    = (float*)alloc(szAct4);
  ushort* ffraw = (ushort*)alloc(szFF2);
  if (off > ws_size) return;   // visible failure, no corruption

  const dim3 tb(32, 8);
  // weight conversions (fused layouts)
  transpose_convert<<<dim3(D_MODEL / 32, D_MODEL / 32), tb, 0, stream>>>(wq, R1, D_MODEL, D_MODEL);
  transpose_convert<<<dim3(D_MODEL / 32, D_MODEL / 32), tb, 0, stream>>>(wk, R1 + (size_t)D_MODEL * D_MODEL, D_MODEL, D_MODEL);
  transpose_convert<<<dim3(D_MODEL / 32, D_MODEL / 32), tb, 0, stream>>>(wv, R1 + 2 * (size_t)D_MODEL * D_MODEL, D_MODEL, D_MODEL);
  transpose_convert<<<dim3(D_MODEL / 32, D_MODEL / 32), tb, 0, stream>>>(wo, wot, D_MODEL, D_MODEL);
  transpose_convert<<<dim3(FF_DIM / 32, D_MODEL / 32), tb, 0, stream>>>(wff, R2, D_MODEL, FF_DIM);
  transpose_convert<<<dim3(FF_DIM / 32, D_MODEL / 32), tb, 0, stream>>>(wup, R2 + (size_t)FF_DIM * D_MODEL, D_MODEL, FF_DIM);

  // attn branch
  rmsnorm_kernel<<<M_ROWS, 256, 0, stream>>>(x, anw, xn);
  gemm8p<0><<<(M_ROWS / 256) * (QKV_N / 256), 512, 0, stream>>>(xn, R1, nullptr, qkv, M_ROWS, QKV_N, D_MODEL);
  // R1 free now -> wout^T (stream-ordered after QKV GEMM)
  transpose_convert<<<dim3(D_MODEL / 32, FF_DIM / 32), tb, 0, stream>>>(wout, R1, FF_DIM, D_MODEL);
  rope_kernel<<<(M_ROWS * NHEAD * 64) / 256, 256, 0, stream>>>(qkv, qkv + D_MODEL, sinp, cosp, QKV_N);
  attn_fwd<<<dim3(SEQ / 16, NHEAD, NBATCH), 64, 0, stream>>>(qkv, qkv + D_MODEL, qkv + 2 * D_MODEL, attnb, QKV_N, D_MODEL);
  gemm8p<1><<<(M_ROWS / 256) * (D_MODEL / 256), 512, 0, stream>>>(attnb, wot, x, x2, M_ROWS, D_MODEL, D_MODEL);

  // ffn branch
  rmsnorm_kernel<<<M_ROWS, 256, 0, stream>>>(x2, fnw, xn);
  gemm8p<0><<<(M_ROWS / 256) * (FF2_N / 256), 512, 0, stream>>>(xn, R2, nullptr, ffraw, M_ROWS, FF2_N, D_MODEL);
  swiglu_kernel<<<dim3(FF_DIM / 2048, M_ROWS), 256, 0, stream>>>(ffraw, qkv /* g */);
  gemm8p<1><<<(M_ROWS / 256) * (D_MODEL / 256), 512, 0, stream>>>(qkv, R1, x2, out, M_ROWS, D_MODEL, FF_DIM);
}